// Round 22
// baseline (91.176 us; speedup 1.0000x reference)
//
#include <hip/hip_runtime.h>
#include <math.h>

typedef __attribute__((ext_vector_type(8))) short short8;
typedef __attribute__((ext_vector_type(4))) float f32x4;
typedef __attribute__((ext_vector_type(16))) float f32x16;

#define BDIM 2
#define T_LEN 2048
#define CDIM 1024
#define NH 16
#define DHEAD 64
#define M_ROWS (BDIM * T_LEN)            // 4096
#define NX (M_ROWS * CDIM)               // 4194304
#define NW (CDIM * CDIM)                 // 1048576

#define QSCL 0.045084220f                // C^-0.5 * log2(e), folded into Wq

__device__ inline unsigned short f2bf(float f) {
    union { float f; unsigned u; } v; v.f = f;
    unsigned r = v.u + 0x7fff + ((v.u >> 16) & 1);   // RNE
    return (unsigned short)(r >> 16);
}

__device__ __forceinline__ void gload16(const unsigned short* g, unsigned short* l) {
    __builtin_amdgcn_global_load_lds(
        (const __attribute__((address_space(1))) void*)g,
        (__attribute__((address_space(3))) void*)l, 16, 0, 0);
}

// ---------------- Kernel 0: fp32 -> bf16 convert (x, Wq*QSCL, Wk, Wv) ----------------
__global__ __launch_bounds__(256) void conv_bf16(
    const float* __restrict__ x, const float* __restrict__ wq,
    const float* __restrict__ wk, const float* __restrict__ wv,
    unsigned short* __restrict__ dst)
{
    int id = blockIdx.x * 256 + threadIdx.x;        // 16B-out chunk id
    const float* s;
    float scl = 1.0f;
    if (id < NX / 8) s = x + (size_t)id * 8;
    else {
        int r = id - NX / 8;
        int wsel = r >> 17;                          // NW/8 = 131072 = 2^17
        int off = r & 131071;
        const float* w = (wsel == 0) ? wq : (wsel == 1) ? wk : wv;
        if (wsel == 0) scl = QSCL;                   // pre-scale Q via Wq
        s = w + (size_t)off * 8;
    }
    float4 a = ((const float4*)s)[0];
    float4 b = ((const float4*)s)[1];
    union { unsigned short u[8]; short8 v; } o;
    o.u[0] = f2bf(a.x * scl); o.u[1] = f2bf(a.y * scl); o.u[2] = f2bf(a.z * scl); o.u[3] = f2bf(a.w * scl);
    o.u[4] = f2bf(b.x * scl); o.u[5] = f2bf(b.y * scl); o.u[6] = f2bf(b.z * scl); o.u[7] = f2bf(b.w * scl);
    *(short8*)(dst + (size_t)id * 8) = o.v;
}

// ---------------- Kernel 1: bf16 QKV GEMM, 128x128 tile, BK=64, TRIPLE-BUFFER ----------------
// Counted vmcnt pipeline (T4): stage kt+2 while computing kt; vmcnt(8) waits only
// kt+1's loads -- kt+2's 8 loads stay in flight ACROSS the raw s_barrier.
__global__ __launch_bounds__(256) void qkv_gemm_f(
    const unsigned short* __restrict__ xb, const unsigned short* __restrict__ wb,
    unsigned short* __restrict__ qkv)
{
    __shared__ __align__(16) unsigned short sh[3][16384];   // 96 KB: [buf][A | B at +8192]
    const int z = blockIdx.z;
    const int m0 = blockIdx.x * 128;
    const int n0 = blockIdx.y * 128;
    const int tid = threadIdx.x;
    const int l = tid & 63, w = tid >> 6;
    const int li = l & 15, g4 = l >> 4;
    const int wr = w >> 1, wc = w & 1;

    const unsigned short* wsrc = wb + (size_t)z * NW;
    f32x4 acc[4][4] = {};

    auto STAGE = [&](int kt, int bf) {
        const int k0 = kt * 64;
        #pragma unroll
        for (int s = 0; s < 4; ++s) {
            int c = w * 256 + s * 64 + l;
            int row = c >> 3, wcol = c & 7;
            int sw = wcol ^ (row & 7);
            gload16(xb + (size_t)(m0 + row) * CDIM + k0 + sw * 8, &sh[bf][(w * 256 + s * 64) * 8]);
            gload16(wsrc + (size_t)(n0 + row) * CDIM + k0 + sw * 8, &sh[bf][8192 + (w * 256 + s * 64) * 8]);
        }
    };
    auto COMPUTE = [&](int cur) {
        const char* A = (const char*)&sh[cur][0];
        const char* Bt = (const char*)&sh[cur][8192];
        __builtin_amdgcn_s_setprio(1);
        #pragma unroll
        for (int ks = 0; ks < 2; ++ks) {
            short8 af[4], bf[4];
            #pragma unroll
            for (int fm = 0; fm < 4; ++fm) {
                int row = wr * 64 + fm * 16 + li;
                int lin = row * 128 + ks * 64 + g4 * 16;
                af[fm] = *(const short8*)(A + (lin ^ ((row & 7) << 4)));
            }
            #pragma unroll
            for (int fn = 0; fn < 4; ++fn) {
                int row = wc * 64 + fn * 16 + li;
                int lin = row * 128 + ks * 64 + g4 * 16;
                bf[fn] = *(const short8*)(Bt + (lin ^ ((row & 7) << 4)));
            }
            #pragma unroll
            for (int fm = 0; fm < 4; ++fm)
                #pragma unroll
                for (int fn = 0; fn < 4; ++fn)
                    acc[fm][fn] = __builtin_amdgcn_mfma_f32_16x16x32_bf16(af[fm], bf[fn], acc[fm][fn], 0, 0, 0);
        }
        __builtin_amdgcn_s_setprio(0);
    };

    // prologue: tiles 0,1 staged; wait tile-0 (8 newest stay in flight)
    STAGE(0, 0);
    STAGE(1, 1);
    asm volatile("s_waitcnt vmcnt(8)" ::: "memory");
    __builtin_amdgcn_s_barrier();

    int cur = 0, bf2 = 2;
    for (int kt = 0; kt < 14; ++kt) {
        STAGE(kt + 2, bf2);
        COMPUTE(cur);
        asm volatile("s_waitcnt vmcnt(8)" ::: "memory");   // kt+1 done; kt+2 in flight
        __builtin_amdgcn_s_barrier();
        cur = (cur == 2) ? 0 : cur + 1;
        bf2 = (bf2 == 2) ? 0 : bf2 + 1;
    }
    COMPUTE(cur);                                          // kt = 14
    asm volatile("s_waitcnt vmcnt(0)" ::: "memory");       // tile 15 done
    __builtin_amdgcn_s_barrier();
    cur = (cur == 2) ? 0 : cur + 1;
    COMPUTE(cur);                                          // kt = 15
    __syncthreads();

    if (z != 2) {
        unsigned short* outp = qkv + (size_t)z * NX;
        #pragma unroll
        for (int fm = 0; fm < 4; ++fm)
            #pragma unroll
            for (int fn = 0; fn < 4; ++fn)
                #pragma unroll
                for (int r = 0; r < 4; ++r) {
                    int m = m0 + wr * 64 + fm * 16 + g4 * 4 + r;
                    int n = n0 + wc * 64 + fn * 16 + li;
                    int b = m >> 11, t = m & 2047;
                    int h = n >> 6, dd = n & 63;
                    outp[((size_t)(b * NH + h) << 17) + ((size_t)t << 6) + dd] = f2bf(acc[fm][fn][r]);
                }
    } else {
        unsigned short (*T)[136] = (unsigned short(*)[136])&sh[0][0];
        #pragma unroll
        for (int fm = 0; fm < 4; ++fm)
            #pragma unroll
            for (int fn = 0; fn < 4; ++fn)
                #pragma unroll
                for (int r = 0; r < 4; ++r) {
                    int ml = wr * 64 + fm * 16 + g4 * 4 + r;
                    int nl = wc * 64 + fn * 16 + li;
                    T[nl][ml] = f2bf(acc[fm][fn][r]);
                }
        __syncthreads();
        int b = m0 >> 11;
        int t0 = m0 & 2047;
        unsigned short* vt = qkv + 2 * (size_t)NX;
        #pragma unroll
        for (int s = 0; s < 8; ++s) {
            int row = tid >> 1;
            int col = ((tid & 1) * 8 + s) * 8;
            int ng = n0 + row;
            int h = ng >> 6, dd = ng & 63;
            *(short8*)(vt + ((size_t)(b * NH + h) * 64 + dd) * T_LEN + t0 + col)
                = *(const short8*)&T[row][col];
        }
    }
}

// ---------------- Kernel 2: causal flash attention, uniform-duration fold (r20 verbatim) ----------------
__global__ __launch_bounds__(512, 2) void attn(
    const unsigned short* __restrict__ qkv, float* __restrict__ out)
{
    // [half][dbuf][K=0/V=1][8192 shorts = 16KB] -> 128 KB
    __shared__ __align__(16) unsigned short KV[2][2][2][8192];

    const int id = blockIdx.x;                        // 0..255
    const int p  = id >> 5;                           // 0..7
    const int rb = id & 31;
    const int bh = (rb & 7) * 4 + (rb >> 3);          // XCD spread: 4 bh per XCD
    const int b = bh >> 4, h = bh & 15;
    const int tid = threadIdx.x;
    const int l = tid & 63, w = tid >> 6;             // w: 0..7
    const int hf = w >> 2, chunk = w & 3;
    const int q31 = l & 31, hi = l >> 5;

    const unsigned short* qp = qkv + (size_t)bh * (T_LEN * DHEAD);
    const unsigned short* kp = qkv + (size_t)NX + (size_t)bh * (T_LEN * DHEAD);
    const unsigned short* vp = qkv + 2 * (size_t)NX + (size_t)bh * (T_LEN * DHEAD); // [dd][t]

    const int qbA = 15 - p;
    int qb = hf ? p : qbA;                            // current q-block for this half
    int q0w = qb * 128 + chunk * 32;
    int qg = q0w + q31;

    short8 aq[4];
    #pragma unroll
    for (int ks = 0; ks < 4; ++ks)
        aq[ks] = *(const short8*)(qp + (size_t)qg * DHEAD + ks * 16 + hi * 8);

    float l_run = 0.f;
    f32x16 acc_oA[2] = {};
    f32x16 acc_oB[2] = {};

    const int nTiles = hf ? 8 : 9;                    // tiles this half computes
    const int swU = hf ? (p + 1) : 16;                // B's phase-switch unit

    auto kv0of = [&](int t) { return ((hf && t > p) ? (t + 8 - p) : t) * 128; };

    auto STAGE = [&](int t) {
        const int kv0 = kv0of(t);
        const int bf = t & 1;
        #pragma unroll
        for (int s = 0; s < 4; ++s) {
            int g = (chunk * 4 + s) * 64 + l;
            int krow = g >> 3, kc = g & 7;
            int ksw = kc ^ (krow & 7);
            gload16(kp + (size_t)(kv0 + krow) * DHEAD + ksw * 8, &KV[hf][bf][0][(chunk * 4 + s) * 512]);
            int sub = g >> 9, cs = g & 511;
            int vrow = cs >> 3, vc = cs & 7;
            int vsw = vc ^ (vrow & 7);
            gload16(vp + (size_t)vrow * T_LEN + kv0 + sub * 64 + vsw * 8, &KV[hf][bf][1][(chunk * 4 + s) * 512]);
        }
    };

    STAGE(0);
    asm volatile("s_waitcnt vmcnt(0)" ::: "memory");
    __syncthreads();

    for (int i = 0; i < 9; ++i) {
        if (hf && i == swU) {
            // ---- finish small q-block: write out, reset, switch to big ----
            float inv = 1.0f / l_run;
            float* ob = out + ((size_t)(b * T_LEN + qg)) * CDIM + h * DHEAD;
            #pragma unroll
            for (int nb2 = 0; nb2 < 2; ++nb2)
                #pragma unroll
                for (int r = 0; r < 16; ++r) {
                    int dd = 32 * nb2 + (r & 3) + 8 * (r >> 2) + 4 * hi;
                    ob[dd] = (acc_oA[nb2][r] + acc_oB[nb2][r]) * inv;
                }
            l_run = 0.f;
            #pragma unroll
            for (int nb2 = 0; nb2 < 2; ++nb2)
                #pragma unroll
                for (int r = 0; r < 16; ++r) { acc_oA[nb2][r] = 0.f; acc_oB[nb2][r] = 0.f; }
            qb = qbA; q0w = qb * 128 + chunk * 32; qg = q0w + q31;
            #pragma unroll
            for (int ks = 0; ks < 4; ++ks)
                aq[ks] = *(const short8*)(qp + (size_t)qg * DHEAD + ks * 16 + hi * 8);
        } else {
            const int t = (hf && i > swU) ? i - 1 : i;
            if (t + 1 < nTiles) STAGE(t + 1);
            const char* Kbase = (const char*)&KV[hf][t & 1][0][0];
            const char* Vbase = (const char*)&KV[hf][t & 1][1][0];
            const int kv0 = kv0of(t);

            // ---- S^T over 128 kv rows ----
            f32x16 sacc[4] = {};
            __builtin_amdgcn_s_setprio(1);
            #pragma unroll
            for (int ks = 0; ks < 4; ++ks) {
                #pragma unroll
                for (int nb = 0; nb < 4; ++nb) {
                    int row = 32 * (nb & 1) + q31;
                    int lin = row * 128 + ks * 32 + hi * 16;
                    short8 ak = *(const short8*)(Kbase + (nb >> 1) * 8192 + (lin ^ ((l & 7) << 4)));
                    sacc[nb] = __builtin_amdgcn_mfma_f32_32x32x16_bf16(ak, aq[ks], sacc[nb], 0, 0, 0);
                }
            }
            __builtin_amdgcn_s_setprio(0);

            // ---- no-max softmax: mask -> exp2 -> sum ----
            const bool domask = (kv0 + 127 > q0w);
            if (domask) {
                #pragma unroll
                for (int nb = 0; nb < 4; ++nb)
                    #pragma unroll
                    for (int r = 0; r < 16; ++r) {
                        int kvg = kv0 + 32 * nb + (r & 3) + 8 * (r >> 2) + 4 * hi;
                        if (kvg > qg) sacc[nb][r] = -INFINITY;
                    }
            }
            float ps[16];
            #pragma unroll
            for (int r = 0; r < 16; ++r) {
                float p0 = exp2f(sacc[0][r]);
                float p1 = exp2f(sacc[1][r]);
                float p2 = exp2f(sacc[2][r]);
                float p3 = exp2f(sacc[3][r]);
                sacc[0][r] = p0; sacc[1][r] = p1; sacc[2][r] = p2; sacc[3][r] = p3;
                ps[r] = (p0 + p1) + (p2 + p3);
            }
            #pragma unroll
            for (int st = 8; st >= 1; st >>= 1)
                #pragma unroll
                for (int r2 = 0; r2 < 8; ++r2)
                    if (r2 < st) ps[r2] += ps[r2 + st];
            l_run += ps[0] + __shfl_xor(ps[0], 32);

            // ---- pack P^T (per sub): cvt_pk + permlane32_swap; PV into split accs ----
            #pragma unroll
            for (int sub = 0; sub < 2; ++sub) {
                unsigned dw[16];
                #pragma unroll
                for (int u = 0; u < 16; ++u) {
                    float lo = sacc[2 * sub + (u >> 3)][(2 * u) & 15];
                    float hif = sacc[2 * sub + (u >> 3)][((2 * u) & 15) + 1];
                    asm("v_cvt_pk_bf16_f32 %0, %1, %2" : "=v"(dw[u]) : "v"(lo), "v"(hif));
                }
                f32x16* accp = sub ? acc_oB : acc_oA;
                __builtin_amdgcn_s_setprio(1);
                #pragma unroll
                for (int ks = 0; ks < 4; ++ks) {
                    unsigned a0 = dw[4 * ks],     b0 = dw[4 * ks + 2];
                    unsigned a1 = dw[4 * ks + 1], b1 = dw[4 * ks + 3];
                    asm("v_permlane32_swap_b32 %0, %1" : "+v"(a0), "+v"(b0));
                    asm("v_permlane32_swap_b32 %0, %1" : "+v"(a1), "+v"(b1));
                    union { unsigned u[4]; short8 v; } pb;
                    pb.u[0] = a0; pb.u[1] = a1; pb.u[2] = b0; pb.u[3] = b1;
                    #pragma unroll
                    for (int nb2 = 0; nb2 < 2; ++nb2) {
                        int row = 32 * nb2 + q31;
                        int lin = row * 128 + ks * 32 + hi * 16;
                        short8 av = *(const short8*)(Vbase + sub * 8192 + (lin ^ ((l & 7) << 4)));
                        accp[nb2] = __builtin_amdgcn_mfma_f32_32x32x16_bf16(av, pb.v, accp[nb2], 0, 0, 0);
                    }
                }
                __builtin_amdgcn_s_setprio(0);
            }
        }
        asm volatile("s_waitcnt vmcnt(0)" ::: "memory");
        __syncthreads();
    }

    // ---- merge big q-block: B publishes, A combines + writes (straight adds) ----
    f32x16 acc_o[2];
    #pragma unroll
    for (int nb2 = 0; nb2 < 2; ++nb2)
        #pragma unroll
        for (int r = 0; r < 16; ++r)
            acc_o[nb2][r] = acc_oA[nb2][r] + acc_oB[nb2][r];

    float* MB = (float*)&KV[0][0][0][0];
    float* slot = MB + (chunk * 64 + l) * 34;
    if (hf) {
        #pragma unroll
        for (int nb2 = 0; nb2 < 2; ++nb2)
            #pragma unroll
            for (int r = 0; r < 16; ++r) slot[nb2 * 16 + r] = acc_o[nb2][r];
        slot[32] = l_run;
    }
    __syncthreads();
    if (!hf) {
        float inv = 1.0f / (l_run + slot[32]);
        float* ob = out + ((size_t)(b * T_LEN + qg)) * CDIM + h * DHEAD;
        #pragma unroll
        for (int nb2 = 0; nb2 < 2; ++nb2)
            #pragma unroll
            for (int r = 0; r < 16; ++r) {
                int dd = 32 * nb2 + (r & 3) + 8 * (r >> 2) + 4 * hi;
                ob[dd] = (acc_o[nb2][r] + slot[nb2 * 16 + r]) * inv;
            }
    }
}

extern "C" void kernel_launch(void* const* d_in, const int* in_sizes, int n_in,
                              void* d_out, int out_size, void* d_ws, size_t ws_size,
                              hipStream_t stream) {
    const float* x  = (const float*)d_in[0];
    const float* Wq = (const float*)d_in[1];
    const float* Wk = (const float*)d_in[2];
    const float* Wv = (const float*)d_in[3];
    float* out = (float*)d_out;

    unsigned short* xb = (unsigned short*)d_out;      // bf16 scratch in d_out (overwritten by attn)
    unsigned short* wb = xb + NX;
    unsigned short* qkv = (unsigned short*)d_ws;

    conv_bf16<<<dim3((NX / 8 + 3 * NW / 8) / 256), dim3(256), 0, stream>>>(x, Wq, Wk, Wv, xb);
    qkv_gemm_f<<<dim3(M_ROWS / 128, CDIM / 128, 3), dim3(256), 0, stream>>>(xb, wb, qkv);
    attn<<<dim3(256), dim3(512), 0, stream>>>(qkv, out);
}

// Round 23
// 82.530 us; speedup vs baseline: 1.1048x; 1.1048x over previous
//
#include <hip/hip_runtime.h>
#include <math.h>

typedef __attribute__((ext_vector_type(8))) short short8;
typedef __attribute__((ext_vector_type(4))) float f32x4;
typedef __attribute__((ext_vector_type(16))) float f32x16;

#define BDIM 2
#define T_LEN 2048
#define CDIM 1024
#define NH 16
#define DHEAD 64
#define M_ROWS (BDIM * T_LEN)            // 4096
#define NX (M_ROWS * CDIM)               // 4194304
#define NW (CDIM * CDIM)                 // 1048576

#define QSCL 0.045084220f                // C^-0.5 * log2(e), folded into Wq

__device__ inline unsigned short f2bf(float f) {
    union { float f; unsigned u; } v; v.f = f;
    unsigned r = v.u + 0x7fff + ((v.u >> 16) & 1);   // RNE
    return (unsigned short)(r >> 16);
}

__device__ __forceinline__ void gload16(const unsigned short* g, unsigned short* l) {
    __builtin_amdgcn_global_load_lds(
        (const __attribute__((address_space(1))) void*)g,
        (__attribute__((address_space(3))) void*)l, 16, 0, 0);
}

// ---------------- Kernel 0: fp32 -> bf16 convert (x, Wq*QSCL, Wk, Wv) ----------------
__global__ __launch_bounds__(256) void conv_bf16(
    const float* __restrict__ x, const float* __restrict__ wq,
    const float* __restrict__ wk, const float* __restrict__ wv,
    unsigned short* __restrict__ dst)
{
    int id = blockIdx.x * 256 + threadIdx.x;        // 16B-out chunk id
    const float* s;
    float scl = 1.0f;
    if (id < NX / 8) s = x + (size_t)id * 8;
    else {
        int r = id - NX / 8;
        int wsel = r >> 17;                          // NW/8 = 131072 = 2^17
        int off = r & 131071;
        const float* w = (wsel == 0) ? wq : (wsel == 1) ? wk : wv;
        if (wsel == 0) scl = QSCL;                   // pre-scale Q via Wq
        s = w + (size_t)off * 8;
    }
    float4 a = ((const float4*)s)[0];
    float4 b = ((const float4*)s)[1];
    union { unsigned short u[8]; short8 v; } o;
    o.u[0] = f2bf(a.x * scl); o.u[1] = f2bf(a.y * scl); o.u[2] = f2bf(a.z * scl); o.u[3] = f2bf(a.w * scl);
    o.u[4] = f2bf(b.x * scl); o.u[5] = f2bf(b.y * scl); o.u[6] = f2bf(b.z * scl); o.u[7] = f2bf(b.w * scl);
    *(short8*)(dst + (size_t)id * 8) = o.v;
}

// ---------------- Kernel 1: bf16 QKV GEMM, 128x128 tile, BK=64, DOUBLE-BUFFERED ----------------
// STAGE(next -> buf^1) issued BEFORE computing buf; one vmcnt(0)+barrier per K-step.
// 64 KB LDS -> 2 blocks/CU (cross-block TLP covers residual latency; r22 showed
// 3-buffer/96KB loses more occupancy than its counted-vmcnt pipeline gains).
__global__ __launch_bounds__(256) void qkv_gemm_f(
    const unsigned short* __restrict__ xb, const unsigned short* __restrict__ wb,
    unsigned short* __restrict__ qkv)
{
    __shared__ __align__(16) unsigned short sh[2][16384];   // [buf][A:0..8191 | B:8192..16383], 64KB
    const int z = blockIdx.z;
    const int m0 = blockIdx.x * 128;
    const int n0 = blockIdx.y * 128;
    const int tid = threadIdx.x;
    const int l = tid & 63, w = tid >> 6;
    const int li = l & 15, g4 = l >> 4;
    const int wr = w >> 1, wc = w & 1;

    const unsigned short* wsrc = wb + (size_t)z * NW;
    f32x4 acc[4][4] = {};

    auto STAGE = [&](int kt, int bf) {
        const int k0 = kt * 64;
        #pragma unroll
        for (int s = 0; s < 4; ++s) {
            int c = w * 256 + s * 64 + l;
            int row = c >> 3, wcol = c & 7;
            int sw = wcol ^ (row & 7);
            gload16(xb + (size_t)(m0 + row) * CDIM + k0 + sw * 8, &sh[bf][(w * 256 + s * 64) * 8]);
            gload16(wsrc + (size_t)(n0 + row) * CDIM + k0 + sw * 8, &sh[bf][8192 + (w * 256 + s * 64) * 8]);
        }
    };

    STAGE(0, 0);
    asm volatile("s_waitcnt vmcnt(0)" ::: "memory");
    __syncthreads();

    for (int kt = 0; kt < 16; ++kt) {
        const int cur = kt & 1;
        if (kt + 1 < 16) STAGE(kt + 1, cur ^ 1);
        const char* A = (const char*)&sh[cur][0];
        const char* Bt = (const char*)&sh[cur][8192];
        __builtin_amdgcn_s_setprio(1);
        #pragma unroll
        for (int ks = 0; ks < 2; ++ks) {
            short8 af[4], bf[4];
            #pragma unroll
            for (int fm = 0; fm < 4; ++fm) {
                int row = wr * 64 + fm * 16 + li;
                int lin = row * 128 + ks * 64 + g4 * 16;
                af[fm] = *(const short8*)(A + (lin ^ ((row & 7) << 4)));
            }
            #pragma unroll
            for (int fn = 0; fn < 4; ++fn) {
                int row = wc * 64 + fn * 16 + li;
                int lin = row * 128 + ks * 64 + g4 * 16;
                bf[fn] = *(const short8*)(Bt + (lin ^ ((row & 7) << 4)));
            }
            #pragma unroll
            for (int fm = 0; fm < 4; ++fm)
                #pragma unroll
                for (int fn = 0; fn < 4; ++fn)
                    acc[fm][fn] = __builtin_amdgcn_mfma_f32_16x16x32_bf16(af[fm], bf[fn], acc[fm][fn], 0, 0, 0);
        }
        __builtin_amdgcn_s_setprio(0);
        asm volatile("s_waitcnt vmcnt(0)" ::: "memory");
        __syncthreads();
    }

    if (z != 2) {
        unsigned short* outp = qkv + (size_t)z * NX;
        #pragma unroll
        for (int fm = 0; fm < 4; ++fm)
            #pragma unroll
            for (int fn = 0; fn < 4; ++fn)
                #pragma unroll
                for (int r = 0; r < 4; ++r) {
                    int m = m0 + wr * 64 + fm * 16 + g4 * 4 + r;
                    int n = n0 + wc * 64 + fn * 16 + li;
                    int b = m >> 11, t = m & 2047;
                    int h = n >> 6, dd = n & 63;
                    outp[((size_t)(b * NH + h) << 17) + ((size_t)t << 6) + dd] = f2bf(acc[fm][fn][r]);
                }
    } else {
        unsigned short (*T)[136] = (unsigned short(*)[136])&sh[0][0];
        #pragma unroll
        for (int fm = 0; fm < 4; ++fm)
            #pragma unroll
            for (int fn = 0; fn < 4; ++fn)
                #pragma unroll
                for (int r = 0; r < 4; ++r) {
                    int ml = wr * 64 + fm * 16 + g4 * 4 + r;
                    int nl = wc * 64 + fn * 16 + li;
                    T[nl][ml] = f2bf(acc[fm][fn][r]);
                }
        __syncthreads();
        int b = m0 >> 11;
        int t0 = m0 & 2047;
        unsigned short* vt = qkv + 2 * (size_t)NX;
        #pragma unroll
        for (int s = 0; s < 8; ++s) {
            int row = tid >> 1;
            int col = ((tid & 1) * 8 + s) * 8;
            int ng = n0 + row;
            int h = ng >> 6, dd = ng & 63;
            *(short8*)(vt + ((size_t)(b * NH + h) * 64 + dd) * T_LEN + t0 + col)
                = *(const short8*)&T[row][col];
        }
    }
}

// ---------------- Kernel 2: causal flash attention, uniform-duration fold ----------------
// 256 blocks (1/CU), q-tile pair (15-p, p); half A: big tile kv [0,9); half B:
// small tile kv [0,p+1) (written directly) then big tile kv [9,16-p). 9 units/block.
// No-max softmax (S bounded via QSCL fold).
__global__ __launch_bounds__(512, 2) void attn(
    const unsigned short* __restrict__ qkv, float* __restrict__ out)
{
    // [half][dbuf][K=0/V=1][8192 shorts = 16KB] -> 128 KB
    __shared__ __align__(16) unsigned short KV[2][2][2][8192];

    const int id = blockIdx.x;                        // 0..255
    const int p  = id >> 5;                           // 0..7
    const int rb = id & 31;
    const int bh = (rb & 7) * 4 + (rb >> 3);          // XCD spread: 4 bh per XCD
    const int b = bh >> 4, h = bh & 15;
    const int tid = threadIdx.x;
    const int l = tid & 63, w = tid >> 6;             // w: 0..7
    const int hf = w >> 2, chunk = w & 3;
    const int q31 = l & 31, hi = l >> 5;

    const unsigned short* qp = qkv + (size_t)bh * (T_LEN * DHEAD);
    const unsigned short* kp = qkv + (size_t)NX + (size_t)bh * (T_LEN * DHEAD);
    const unsigned short* vp = qkv + 2 * (size_t)NX + (size_t)bh * (T_LEN * DHEAD); // [dd][t]

    const int qbA = 15 - p;
    int qb = hf ? p : qbA;                            // current q-block for this half
    int q0w = qb * 128 + chunk * 32;
    int qg = q0w + q31;

    short8 aq[4];
    #pragma unroll
    for (int ks = 0; ks < 4; ++ks)
        aq[ks] = *(const short8*)(qp + (size_t)qg * DHEAD + ks * 16 + hi * 8);

    float l_run = 0.f;
    f32x16 acc_oA[2] = {};
    f32x16 acc_oB[2] = {};

    const int nTiles = hf ? 8 : 9;                    // tiles this half computes
    const int swU = hf ? (p + 1) : 16;                // B's phase-switch unit

    auto kv0of = [&](int t) { return ((hf && t > p) ? (t + 8 - p) : t) * 128; };

    auto STAGE = [&](int t) {
        const int kv0 = kv0of(t);
        const int bf = t & 1;
        #pragma unroll
        for (int s = 0; s < 4; ++s) {
            int g = (chunk * 4 + s) * 64 + l;
            int krow = g >> 3, kc = g & 7;
            int ksw = kc ^ (krow & 7);
            gload16(kp + (size_t)(kv0 + krow) * DHEAD + ksw * 8, &KV[hf][bf][0][(chunk * 4 + s) * 512]);
            int sub = g >> 9, cs = g & 511;
            int vrow = cs >> 3, vc = cs & 7;
            int vsw = vc ^ (vrow & 7);
            gload16(vp + (size_t)vrow * T_LEN + kv0 + sub * 64 + vsw * 8, &KV[hf][bf][1][(chunk * 4 + s) * 512]);
        }
    };

    STAGE(0);
    asm volatile("s_waitcnt vmcnt(0)" ::: "memory");
    __syncthreads();

    for (int i = 0; i < 9; ++i) {
        if (hf && i == swU) {
            // ---- finish small q-block: write out, reset, switch to big ----
            float inv = 1.0f / l_run;
            float* ob = out + ((size_t)(b * T_LEN + qg)) * CDIM + h * DHEAD;
            #pragma unroll
            for (int nb2 = 0; nb2 < 2; ++nb2)
                #pragma unroll
                for (int r = 0; r < 16; ++r) {
                    int dd = 32 * nb2 + (r & 3) + 8 * (r >> 2) + 4 * hi;
                    ob[dd] = (acc_oA[nb2][r] + acc_oB[nb2][r]) * inv;
                }
            l_run = 0.f;
            #pragma unroll
            for (int nb2 = 0; nb2 < 2; ++nb2)
                #pragma unroll
                for (int r = 0; r < 16; ++r) { acc_oA[nb2][r] = 0.f; acc_oB[nb2][r] = 0.f; }
            qb = qbA; q0w = qb * 128 + chunk * 32; qg = q0w + q31;
            #pragma unroll
            for (int ks = 0; ks < 4; ++ks)
                aq[ks] = *(const short8*)(qp + (size_t)qg * DHEAD + ks * 16 + hi * 8);
        } else {
            const int t = (hf && i > swU) ? i - 1 : i;
            if (t + 1 < nTiles) STAGE(t + 1);
            const char* Kbase = (const char*)&KV[hf][t & 1][0][0];
            const char* Vbase = (const char*)&KV[hf][t & 1][1][0];
            const int kv0 = kv0of(t);

            // ---- S^T over 128 kv rows ----
            f32x16 sacc[4] = {};
            __builtin_amdgcn_s_setprio(1);
            #pragma unroll
            for (int ks = 0; ks < 4; ++ks) {
                #pragma unroll
                for (int nb = 0; nb < 4; ++nb) {
                    int row = 32 * (nb & 1) + q31;
                    int lin = row * 128 + ks * 32 + hi * 16;
                    short8 ak = *(const short8*)(Kbase + (nb >> 1) * 8192 + (lin ^ ((l & 7) << 4)));
                    sacc[nb] = __builtin_amdgcn_mfma_f32_32x32x16_bf16(ak, aq[ks], sacc[nb], 0, 0, 0);
                }
            }
            __builtin_amdgcn_s_setprio(0);

            // ---- no-max softmax: mask -> exp2 -> sum ----
            const bool domask = (kv0 + 127 > q0w);
            if (domask) {
                #pragma unroll
                for (int nb = 0; nb < 4; ++nb)
                    #pragma unroll
                    for (int r = 0; r < 16; ++r) {
                        int kvg = kv0 + 32 * nb + (r & 3) + 8 * (r >> 2) + 4 * hi;
                        if (kvg > qg) sacc[nb][r] = -INFINITY;
                    }
            }
            float ps[16];
            #pragma unroll
            for (int r = 0; r < 16; ++r) {
                float p0 = exp2f(sacc[0][r]);
                float p1 = exp2f(sacc[1][r]);
                float p2 = exp2f(sacc[2][r]);
                float p3 = exp2f(sacc[3][r]);
                sacc[0][r] = p0; sacc[1][r] = p1; sacc[2][r] = p2; sacc[3][r] = p3;
                ps[r] = (p0 + p1) + (p2 + p3);
            }
            #pragma unroll
            for (int st = 8; st >= 1; st >>= 1)
                #pragma unroll
                for (int r2 = 0; r2 < 8; ++r2)
                    if (r2 < st) ps[r2] += ps[r2 + st];
            l_run += ps[0] + __shfl_xor(ps[0], 32);

            // ---- pack P^T (per sub): cvt_pk + permlane32_swap; PV into split accs ----
            #pragma unroll
            for (int sub = 0; sub < 2; ++sub) {
                unsigned dw[16];
                #pragma unroll
                for (int u = 0; u < 16; ++u) {
                    float lo = sacc[2 * sub + (u >> 3)][(2 * u) & 15];
                    float hif = sacc[2 * sub + (u >> 3)][((2 * u) & 15) + 1];
                    asm("v_cvt_pk_bf16_f32 %0, %1, %2" : "=v"(dw[u]) : "v"(lo), "v"(hif));
                }
                f32x16* accp = sub ? acc_oB : acc_oA;
                __builtin_amdgcn_s_setprio(1);
                #pragma unroll
                for (int ks = 0; ks < 4; ++ks) {
                    unsigned a0 = dw[4 * ks],     b0 = dw[4 * ks + 2];
                    unsigned a1 = dw[4 * ks + 1], b1 = dw[4 * ks + 3];
                    asm("v_permlane32_swap_b32 %0, %1" : "+v"(a0), "+v"(b0));
                    asm("v_permlane32_swap_b32 %0, %1" : "+v"(a1), "+v"(b1));
                    union { unsigned u[4]; short8 v; } pb;
                    pb.u[0] = a0; pb.u[1] = a1; pb.u[2] = b0; pb.u[3] = b1;
                    #pragma unroll
                    for (int nb2 = 0; nb2 < 2; ++nb2) {
                        int row = 32 * nb2 + q31;
                        int lin = row * 128 + ks * 32 + hi * 16;
                        short8 av = *(const short8*)(Vbase + sub * 8192 + (lin ^ ((l & 7) << 4)));
                        accp[nb2] = __builtin_amdgcn_mfma_f32_32x32x16_bf16(av, pb.v, accp[nb2], 0, 0, 0);
                    }
                }
                __builtin_amdgcn_s_setprio(0);
            }
        }
        asm volatile("s_waitcnt vmcnt(0)" ::: "memory");
        __syncthreads();
    }

    // ---- merge big q-block: B publishes, A combines + writes (straight adds) ----
    f32x16 acc_o[2];
    #pragma unroll
    for (int nb2 = 0; nb2 < 2; ++nb2)
        #pragma unroll
        for (int r = 0; r < 16; ++r)
            acc_o[nb2][r] = acc_oA[nb2][r] + acc_oB[nb2][r];

    float* MB = (float*)&KV[0][0][0][0];
    float* slot = MB + (chunk * 64 + l) * 34;
    if (hf) {
        #pragma unroll
        for (int nb2 = 0; nb2 < 2; ++nb2)
            #pragma unroll
            for (int r = 0; r < 16; ++r) slot[nb2 * 16 + r] = acc_o[nb2][r];
        slot[32] = l_run;
    }
    __syncthreads();
    if (!hf) {
        float inv = 1.0f / (l_run + slot[32]);
        float* ob = out + ((size_t)(b * T_LEN + qg)) * CDIM + h * DHEAD;
        #pragma unroll
        for (int nb2 = 0; nb2 < 2; ++nb2)
            #pragma unroll
            for (int r = 0; r < 16; ++r) {
                int dd = 32 * nb2 + (r & 3) + 8 * (r >> 2) + 4 * hi;
                ob[dd] = (acc_o[nb2][r] + slot[nb2 * 16 + r]) * inv;
            }
    }
}

extern "C" void kernel_launch(void* const* d_in, const int* in_sizes, int n_in,
                              void* d_out, int out_size, void* d_ws, size_t ws_size,
                              hipStream_t stream) {
    const float* x  = (const float*)d_in[0];
    const float* Wq = (const float*)d_in[1];
    const float* Wk = (const float*)d_in[2];
    const float* Wv = (const float*)d_in[3];
    float* out = (float*)d_out;

    unsigned short* xb = (unsigned short*)d_out;      // bf16 scratch in d_out (overwritten by attn)
    unsigned short* wb = xb + NX;
    unsigned short* qkv = (unsigned short*)d_ws;

    conv_bf16<<<dim3((NX / 8 + 3 * NW / 8) / 256), dim3(256), 0, stream>>>(x, Wq, Wk, Wv, xb);
    qkv_gemm_f<<<dim3(M_ROWS / 128, CDIM / 128, 3), dim3(256), 0, stream>>>(xb, wb, qkv);
    attn<<<dim3(256), dim3(512), 0, stream>>>(qkv, out);
}